// Round 1
// 248.490 us; speedup vs baseline: 1.0133x; 1.0133x over previous
//
#include <hip/hip_runtime.h>

// P=1,048,576 params; E=8,388,608 edges; T=4,194,304 bytes; N=2,097,152 tokens.
//
// Measured HW facts driving this design:
//  - global atomicAdd caps at ~20.4 G/s regardless of locality (R1-R3) -> no
//    global atomics in hot paths; all accumulation in LDS.
//  - isolated small scattered stores cause ~3x write RMW amplification (R4) ->
//    scattered global writes staged via in-LDS counting sort, written as runs.
//  - NT loads on read-once input streams keep the fp table L2-resident (R10).
//  - R11 cache-policy split: intermediates (recs, rec2) written with normal
//    cached stores so L2 write-combines and they stay L3-resident.
//  - R12 (this round): phaseA was latency-bound (VALUBusy 8.5%, HBM 30%,
//    occ 66%): dependent NT-load -> fp-gather chain, 2 blocks/CU, no
//    cross-chunk overlap. Fix: (a) records carry pidx (20b) instead of fx so
//    phaseA does NO gathers (pure stream sort); fx is computed in phaseC
//    pass 1 where the loop pipelines trivially. (b) persistent 2-chunk blocks
//    with register-reuse prefetch of the next chunk's streams. (c) phaseC rec
//    reads are NT so the 134MB rec stream doesn't thrash the 4MB/XCD fp table.
//
// rec64 = pos_low(13) | tok(21)<<13 | pidx(21)<<34 | bucket(9)<<55.
// acc u32 = cnt*2^26 + sum(fx), fx = round(fp[pidx] * 2^21)  (cnt<=~25).
// rec2 = tok_low(13) | wfx<<13,  wfx = round(w * 2^19) (19-bit signed).

typedef unsigned long long u64;
typedef unsigned int uint;
typedef int  vi4  __attribute__((ext_vector_type(4)));
typedef unsigned long long uv2 __attribute__((ext_vector_type(2)));

constexpr int NB   = 512;        // byte buckets  (bpos >> 13)
constexpr int PPB  = 8192;       // positions per byte bucket
constexpr int NB2  = 256;        // token buckets (tok >> 13)
constexpr int TOKB = 8192;       // tokens per token bucket
constexpr int CAP  = 17408;      // per-bucket capacity (mean 16384 + 8 sigma)
constexpr int CAP2 = 34816;      // per-token-bucket capacity (mean 32768 + 11s)

constexpr float V_SCALE = 2097152.0f;        // 2^21
constexpr float V_INV   = 1.0f / 2097152.0f;
constexpr float W_SCALE = 524288.0f;         // 2^19
constexpr float W_INV   = 1.0f / 524288.0f;

// Exclusive scan of 512 LDS entries by wave 0 only. lbase[512] = total.
__device__ __forceinline__ void wave_scan512(const uint* hist, uint* lbase,
                                             int t) {
    if (t < 64) {
        uint h[8];
        uint run = 0;
        #pragma unroll
        for (int j = 0; j < 8; ++j) { h[j] = run; run += hist[t * 8 + j]; }
        uint tot = run, inc = tot;
        #pragma unroll
        for (int d = 1; d < 64; d <<= 1) {
            uint up = __shfl_up(inc, d, 64);
            if (t >= d) inc += up;
        }
        uint excl = inc - tot;
        #pragma unroll
        for (int j = 0; j < 8; ++j) lbase[t * 8 + j] = excl + h[j];
        if (t == 63) lbase[512] = inc;
    }
}

// Exclusive scan of 256 LDS entries by wave 0 only. lbase[256] = total.
__device__ __forceinline__ void wave_scan256(const uint* hist, uint* lbase,
                                             int t) {
    if (t < 64) {
        uint h[4];
        uint run = 0;
        #pragma unroll
        for (int j = 0; j < 4; ++j) { h[j] = run; run += hist[t * 4 + j]; }
        uint tot = run, inc = tot;
        #pragma unroll
        for (int d = 1; d < 64; d <<= 1) {
            uint up = __shfl_up(inc, d, 64);
            if (t >= d) inc += up;
        }
        uint excl = inc - tot;
        #pragma unroll
        for (int j = 0; j < 4; ++j) lbase[t * 4 + j] = excl + h[j];
        if (t == 63) lbase[256] = inc;
    }
}

// ---------------- Phase A: bin edges into 512 byte-buckets ----------------
// Gather-free streaming sort; persistent blocks, 2 chunks each, prefetched.
constexpr int A_THREADS = 1024;
constexpr int A_EPT     = 8;
constexpr int A_CHUNK   = A_THREADS * A_EPT;   // 8192
constexpr int A_CPB     = 2;                   // chunks per block

__global__ __launch_bounds__(A_THREADS, 8) void phaseA(
    const int* __restrict__ pidx, const int* __restrict__ bpos,
    const int* __restrict__ tidx, u64* __restrict__ recs,
    uint* __restrict__ gcur, int E)
{
    __shared__ u64 stage[A_CHUNK];                 // 64 KB
    __shared__ uint hist[NB], lcur[NB], gbase[NB], lbase[NB + 1];  // ~8 KB
    int t = threadIdx.x;

    int c = blockIdx.x * A_CPB;
    int be0 = c * A_CHUNK + t * A_EPT;
    bool vec = (be0 + A_EPT) <= E;

    // initial NT loads of all three read-once streams for chunk 0
    vi4 b0, b1, p0, p1, k0, k1;
    if (vec) {
        b0 = __builtin_nontemporal_load((const vi4*)(bpos + be0));
        b1 = __builtin_nontemporal_load((const vi4*)(bpos + be0 + 4));
        p0 = __builtin_nontemporal_load((const vi4*)(pidx + be0));
        p1 = __builtin_nontemporal_load((const vi4*)(pidx + be0 + 4));
        k0 = __builtin_nontemporal_load((const vi4*)(tidx + be0));
        k1 = __builtin_nontemporal_load((const vi4*)(tidx + be0 + 4));
    }

    for (int cc = 0; cc < A_CPB; ++cc, ++c) {
        if (t < NB) { hist[t] = 0u; lcur[t] = 0u; }
        __syncthreads();

        int be = c * A_CHUNK + t * A_EPT;
        if (vec) {
            atomicAdd(&hist[((uint)b0.x) >> 13], 1u);
            atomicAdd(&hist[((uint)b0.y) >> 13], 1u);
            atomicAdd(&hist[((uint)b0.z) >> 13], 1u);
            atomicAdd(&hist[((uint)b0.w) >> 13], 1u);
            atomicAdd(&hist[((uint)b1.x) >> 13], 1u);
            atomicAdd(&hist[((uint)b1.y) >> 13], 1u);
            atomicAdd(&hist[((uint)b1.z) >> 13], 1u);
            atomicAdd(&hist[((uint)b1.w) >> 13], 1u);
        } else {
            for (int j = 0; j < A_EPT; ++j) {
                int e = be + j;
                if (e < E) atomicAdd(&hist[((uint)bpos[e]) >> 13], 1u);
            }
        }
        __syncthreads();

        // wave 0 scans; waves 8-15 issue the global cursor atomics concurrently.
        wave_scan512(hist, lbase, t);
        if (t >= 512) gbase[t - 512] = atomicAdd(&gcur[t - 512], hist[t - 512]);
        __syncthreads();

        // emit into LDS-staged counting sort (pure register/LDS, no value)
        auto emit = [&](int p, int tk, int pi) {
            uint b = ((uint)p) >> 13;
            u64 rec = (u64)(uint)(p & (PPB - 1))
                    | ((u64)(uint)tk << 13)
                    | ((u64)(uint)pi << 34)
                    | ((u64)b << 55);
            uint off = lbase[b] + atomicAdd(&lcur[b], 1u);
            stage[off] = rec;
        };
        if (vec) {
            emit(b0.x, k0.x, p0.x); emit(b0.y, k0.y, p0.y);
            emit(b0.z, k0.z, p0.z); emit(b0.w, k0.w, p0.w);
            emit(b1.x, k1.x, p1.x); emit(b1.y, k1.y, p1.y);
            emit(b1.z, k1.z, p1.z); emit(b1.w, k1.w, p1.w);
        } else {
            for (int j = 0; j < A_EPT; ++j) {
                int e = be + j;
                if (e < E) emit(bpos[e], tidx[e], pidx[e]);
            }
        }

        // prefetch next chunk's streams NOW (registers are dead after emit);
        // the ~900cy HBM latency drains under the barrier + writeout below.
        bool nvec = false;
        if (cc + 1 < A_CPB) {
            int nbe = (c + 1) * A_CHUNK + t * A_EPT;
            nvec = (nbe + A_EPT) <= E;
            if (nvec) {
                b0 = __builtin_nontemporal_load((const vi4*)(bpos + nbe));
                b1 = __builtin_nontemporal_load((const vi4*)(bpos + nbe + 4));
                p0 = __builtin_nontemporal_load((const vi4*)(pidx + nbe));
                p1 = __builtin_nontemporal_load((const vi4*)(pidx + nbe + 4));
                k0 = __builtin_nontemporal_load((const vi4*)(tidx + nbe));
                k1 = __builtin_nontemporal_load((const vi4*)(tidx + nbe + 4));
            }
        }
        __syncthreads();

        // write-out: bucket id from record bits; NORMAL cached stores
        // -> L2 write-combines runs, records stay L3-resident for phaseC.
        uint total = lbase[NB];
        for (uint i = t; i < total; i += A_THREADS) {
            u64 rc = stage[i];
            int b = (int)(rc >> 55);
            uint dst = gbase[b] + (i - lbase[b]);
            if (dst < (uint)CAP)
                recs[(size_t)b * CAP + dst] = rc;
        }
        vec = nvec;
        // no trailing barrier needed: next iteration's hist/lcur reset touches
        // disjoint LDS, and its own __syncthreads orders everything after.
    }
}

// ------- Phase C: per byte-bucket accumulate + emit token-bucket recs -------
constexpr int C_THREADS = 1024;
constexpr int C_CHUNK   = 8192;
constexpr int C_MAXCH   = (CAP + C_CHUNK - 1) / C_CHUNK;   // 3

__global__ __launch_bounds__(C_THREADS, 8) void phaseC(
    const float* __restrict__ fp,
    const u64* __restrict__ recs, const uint* __restrict__ gcur,
    uint* __restrict__ rec2, uint* __restrict__ gcur2)
{
    __shared__ uint acc[PPB];               // 32 KB
    __shared__ uint stage2[C_CHUNK];        // 32 KB
    __shared__ uint histc[C_MAXCH][NB2];    // 3 KB
    __shared__ uint lcur[NB2], gb[NB2], lbase[NB2 + 1];   // ~3 KB
    int t = threadIdx.x;
    int b = blockIdx.x;
    for (int i = t; i < PPB; i += C_THREADS) acc[i] = 0u;
    for (int i = t; i < C_MAXCH * NB2; i += C_THREADS) (&histc[0][0])[i] = 0u;
    if (t < NB2) lcur[t] = 0u;
    __syncthreads();

    uint n = min(gcur[b], (uint)CAP);
    const u64* r = recs + (size_t)b * CAP;

    // pass 1: gather fp[pidx] (cached -> stays in L2), quantize, accumulate,
    // + per-chunk token histograms. rec reads are NT so the 134MB rec stream
    // doesn't evict the 4MB fp table from the XCD's L2.
    auto process = [&](u64 rc, uint ch) {
        uint pos = (uint)rc & (PPB - 1);
        uint pi  = (uint)(rc >> 34) & 0x1FFFFFu;
        int  fx  = (int)rintf(fp[pi] * V_SCALE);
        atomicAdd(&acc[pos], (uint)((1 << 26) + fx));
        atomicAdd(&histc[ch][(uint)(rc >> 26) & 0xFFu], 1u);  // tok>>13
    };
    uint np = n >> 1;
    for (uint i = t; i < np; i += C_THREADS) {
        uv2 rr = __builtin_nontemporal_load(((const uv2*)r) + i);
        uint ch = (2u * i) / C_CHUNK;
        process(rr.x, ch); process(rr.y, ch);
    }
    for (uint i = 2u * np + t; i < n; i += C_THREADS)
        process(__builtin_nontemporal_load(r + i), i / C_CHUNK);
    __syncthreads();

    // ONE global-cursor atomic per bucket per block (wave 8), overlapped
    // with wave 0's chunk-0 scan below.
    if (t >= 512 && t < 512 + NB2) {
        int tb = t - 512;
        uint tot = histc[0][tb];
        #pragma unroll
        for (int c = 1; c < C_MAXCH; ++c) tot += histc[c][tb];
        gb[tb] = atomicAdd(&gcur2[tb], tot);
    }

    // pass 2: chunked decode + LDS-staged emit + wave-per-bucket write-out
    uint ch = 0;
    for (uint c0 = 0; c0 < n; c0 += C_CHUNK, ++ch) {
        uint m = min((uint)C_CHUNK, n - c0);
        wave_scan256(histc[ch], lbase, t);
        __syncthreads();
        for (uint i = t; i < m; i += C_THREADS) {
            u64 rc = __builtin_nontemporal_load(r + c0 + i);
            uint pos = (uint)rc & (PPB - 1);
            uint tok = (uint)(rc >> 13) & 0x1FFFFFu;
            uint a = acc[pos];
            uint c = (a + (1u << 25)) >> 26;        // exact count >= 1
            int s = (int)(a - (c << 26));           // signed sum * 2^21
            float w = (float)s * V_INV / (float)c;
            int wfx = (int)rintf(w * W_SCALE);
            uint tb = tok >> 13;
            uint off = lbase[tb] + atomicAdd(&lcur[tb], 1u);
            stage2[off] = (tok & (TOKB - 1)) | ((uint)wfx << 13);
        }
        __syncthreads();
        // write-out: wave w copies buckets w, w+16, ... as contiguous runs
        // (normal cached stores -> rec2 stays L3-resident for phaseD)
        int w = t >> 6, lane = t & 63;
        for (int tb = w; tb < NB2; tb += 16) {
            uint base = lbase[tb];
            uint len  = lbase[tb + 1] - base;
            uint g    = gb[tb];
            for (uint j = lane; j < len; j += 64) {
                uint dst = g + j;
                if (dst < (uint)CAP2)
                    rec2[(size_t)tb * CAP2 + dst] = stage2[base + j];
            }
        }
        __syncthreads();
        if (t < NB2) { gb[t] += histc[ch][t]; lcur[t] = 0u; }
        __syncthreads();
    }
}

// ---------------- Phase D: per token-bucket reduce + output ----------------
constexpr int D_THREADS = 1024;

__global__ __launch_bounds__(D_THREADS) void phaseD(
    const uint* __restrict__ rec2, const uint* __restrict__ gcur2,
    float* __restrict__ out, int N)
{
    __shared__ int facc[TOKB];   // 32 KB
    int t = threadIdx.x;
    int b = blockIdx.x;
    for (int i = t; i < TOKB; i += D_THREADS) facc[i] = 0;
    __syncthreads();
    uint n = min(gcur2[b], (uint)CAP2);
    const uint* r = rec2 + (size_t)b * CAP2;
    uint nq = n >> 2;
    for (uint i = t; i < nq; i += D_THREADS) {
        uint4 q = ((const uint4*)r)[i];
        atomicAdd(&facc[q.x & (TOKB - 1)], ((int)q.x) >> 13);
        atomicAdd(&facc[q.y & (TOKB - 1)], ((int)q.y) >> 13);
        atomicAdd(&facc[q.z & (TOKB - 1)], ((int)q.z) >> 13);
        atomicAdd(&facc[q.w & (TOKB - 1)], ((int)q.w) >> 13);
    }
    for (uint i = 4u * nq + t; i < n; i += D_THREADS) {
        uint rc = r[i];
        atomicAdd(&facc[rc & (TOKB - 1)], ((int)rc) >> 13);
    }
    __syncthreads();
    int base = b * TOKB;
    for (int i = t; i < TOKB; i += D_THREADS) {
        int idx = base + i;
        if (idx < N)
            __builtin_nontemporal_store((float)facc[i] * W_INV, &out[idx]);
    }
}

// ---------------- fallback (R2 path) if workspace too small ----------------
__global__ void fb_scatter(const float* __restrict__ fp,
                           const int* __restrict__ pidx,
                           const int* __restrict__ bpos,
                           u64* __restrict__ bacc, int E) {
    int e = blockIdx.x * blockDim.x + threadIdx.x;
    if (e < E) {
        float v = fp[pidx[e]];
        long long fx = (long long)rintf(v * 4294967296.0f);
        atomicAdd(&bacc[bpos[e]], (1ULL << 39) + (u64)fx);
    }
}

__global__ void fb_tokens(const u64* __restrict__ bacc,
                          const int* __restrict__ bpos,
                          const int* __restrict__ tidx,
                          float* __restrict__ out, int E) {
    int e = blockIdx.x * blockDim.x + threadIdx.x;
    if (e < E) {
        u64 v = bacc[bpos[e]];
        long long cnt = (long long)((v + (1ULL << 38)) >> 39);
        long long s   = (long long)(v - ((u64)cnt << 39));
        atomicAdd(&out[tidx[e]], (float)s * (1.0f / 4294967296.0f) / (float)cnt);
    }
}

extern "C" void kernel_launch(void* const* d_in, const int* in_sizes, int n_in,
                              void* d_out, int out_size, void* d_ws, size_t ws_size,
                              hipStream_t stream) {
    const float* flat_params   = (const float*)d_in[0];
    const int*   occ_param_idx = (const int*)d_in[1];
    const int*   occ_byte_pos  = (const int*)d_in[2];
    const int*   occ_token_idx = (const int*)d_in[3];

    const int P = in_sizes[0];            // 1,048,576
    const int E = in_sizes[1];            // 8,388,608
    const int N = out_size;               // 2,097,152

    const size_t REC_BYTES  = (size_t)NB  * CAP  * 8;   // 71.3 MB
    const size_t REC2_BYTES = (size_t)NB2 * CAP2 * 4;   // 35.7 MB
    const size_t NEED = 4096 + REC_BYTES + REC2_BYTES;  // ~107 MB

    if (ws_size >= NEED && N <= NB2 * TOKB && P <= (1 << 21)) {
        uint* gcur  = (uint*)d_ws;                  // 2 KB
        uint* gcur2 = (uint*)((char*)d_ws + 2048);  // 1 KB
        u64* recs = (u64*)((char*)d_ws + 4096);
        uint* rec2 = (uint*)((char*)d_ws + 4096 + REC_BYTES);

        (void)hipMemsetAsync(d_ws, 0, 4096, stream);   // both cursor arrays

        int nchunks = (E + A_CHUNK - 1) / A_CHUNK;          // 1024
        int gridA = (nchunks + A_CPB - 1) / A_CPB;          // 512
        phaseA<<<gridA, A_THREADS, 0, stream>>>(occ_param_idx, occ_byte_pos,
                                                occ_token_idx, recs, gcur, E);
        phaseC<<<NB, C_THREADS, 0, stream>>>(flat_params, recs, gcur,
                                             rec2, gcur2);
        phaseD<<<NB2, D_THREADS, 0, stream>>>(rec2, gcur2, (float*)d_out, N);
    } else {
        u64* bacc = (u64*)d_ws;
        (void)hipMemsetAsync(bacc, 0, (size_t)4194304 * 8, stream);
        (void)hipMemsetAsync(d_out, 0, (size_t)N * sizeof(float), stream);
        int gridE = (E + 255) / 256;
        fb_scatter<<<gridE, 256, 0, stream>>>(flat_params, occ_param_idx,
                                              occ_byte_pos, bacc, E);
        fb_tokens<<<gridE, 256, 0, stream>>>(bacc, occ_byte_pos,
                                             occ_token_idx, (float*)d_out, E);
    }
}